// Round 2
// baseline (244.340 us; speedup 1.0000x reference)
//
#include <hip/hip_runtime.h>
#include <hip/hip_bf16.h>

// out[b, c, i, j] = x[b, c, i, j] + pe_flat[g],  g = c*4096 + i*64 + j (flat idx per batch)
// pe_flat is the [H=64, W=64, C=256] pe tensor viewed flat (reference's raw reshape), so
// for flat-in-batch element index g:
//   c2 = g & 255, j2 = (g >> 8) & 63, i2 = (g >> 14) & 63
//   pe = jj*W[c2,0] + ii*W[c2,1] + (1-jj)*W[c2,2] + (1-ii)*W[c2,3] + b[c2]
//      = jj*(W0-W2) + ii*(W1-W3) + (W2+W3+b),   jj = j2/63, ii = i2/63
// pe is batch-independent. Grid-stride loop with stride = 2^20 float4 = exactly 4 batches,
// so each thread's within-batch position is loop-invariant -> pe computed once in registers.

#define TOTAL_F4   (1u << 23)        // 32*256*64*64 floats / 4
#define THREADS    256
#define BLOCKS     4096              // 2^20 threads total
#define STRIDE_F4  (1u << 20)        // BLOCKS*THREADS; = 4 batches worth of float4
#define ITERS      8                 // TOTAL_F4 / STRIDE_F4

__global__ __launch_bounds__(THREADS) void pe_add_kernel(
    const float* __restrict__ x,
    const float* __restrict__ Wm,    // [256, 4] row-major
    const float* __restrict__ bias,  // [256]
    float* __restrict__ out)
{
    const unsigned t = blockIdx.x * (unsigned)THREADS + threadIdx.x;   // [0, 2^20)

    // Within-batch position (invariant across the 8 iterations below).
    const unsigned p  = t & ((1u << 18) - 1u);   // float4 index within a batch
    const unsigned g  = p << 2;                  // element index within a batch
    const unsigned c2 = g & 255u;                // channel of first element (multiple of 4)
    const unsigned j2 = (g >> 8) & 63u;
    const unsigned i2 = (g >> 14) & 63u;

    const float u = (float)j2 * (1.0f / 63.0f);
    const float v = (float)i2 * (1.0f / 63.0f);

    // W rows c2 .. c2+3 : 4 aligned float4 loads (Wm is [256][4], 16B rows).
    const float4* Wrows = reinterpret_cast<const float4*>(Wm);
    const float4 wa = Wrows[c2 + 0];
    const float4 wb = Wrows[c2 + 1];
    const float4 wc = Wrows[c2 + 2];
    const float4 wd = Wrows[c2 + 3];

    const float pe0 = u * (wa.x - wa.z) + v * (wa.y - wa.w) + (wa.z + wa.w + bias[c2 + 0]);
    const float pe1 = u * (wb.x - wb.z) + v * (wb.y - wb.w) + (wb.z + wb.w + bias[c2 + 1]);
    const float pe2 = u * (wc.x - wc.z) + v * (wc.y - wc.w) + (wc.z + wc.w + bias[c2 + 2]);
    const float pe3 = u * (wd.x - wd.z) + v * (wd.y - wd.w) + (wd.z + wd.w + bias[c2 + 3]);

    const float4* xp = reinterpret_cast<const float4*>(x);
    float4*       op = reinterpret_cast<float4*>(out);

#pragma unroll
    for (unsigned n = 0; n < ITERS; ++n) {
        const size_t f = (size_t)t + (size_t)n * STRIDE_F4;   // covers [0, 2^23) exactly once
        float4 xv = xp[f];
        float4 ov;
        ov.x = xv.x + pe0;
        ov.y = xv.y + pe1;
        ov.z = xv.z + pe2;
        ov.w = xv.w + pe3;
        op[f] = ov;
    }
}

extern "C" void kernel_launch(void* const* d_in, const int* in_sizes, int n_in,
                              void* d_out, int out_size, void* d_ws, size_t ws_size,
                              hipStream_t stream) {
    const float* x    = (const float*)d_in[0];  // [32, 256, 64, 64] fp32
    const float* Wm   = (const float*)d_in[1];  // [256, 4] fp32
    const float* bias = (const float*)d_in[2];  // [256] fp32
    float* out = (float*)d_out;                 // [32, 256, 64, 64] fp32

    pe_add_kernel<<<dim3(BLOCKS), dim3(THREADS), 0, stream>>>(x, Wm, bias, out);
}

// Round 4
// 237.315 us; speedup vs baseline: 1.0296x; 1.0296x over previous
//
#include <hip/hip_runtime.h>
#include <hip/hip_bf16.h>

// out[b, c, i, j] = x[b, c, i, j] + pe_flat[g],  g = c*4096 + i*64 + j (flat idx per batch)
// pe_flat is the [H=64, W=64, C=256] pe tensor viewed flat (reference's raw reshape):
//   c2 = g & 255, j2 = (g >> 8) & 63, i2 = (g >> 14) & 63
//   pe = jj*(W0-W2) + ii*(W1-W3) + (W2+W3+b),   jj = j2/63, ii = i2/63
// pe is batch-independent. Grid stride = 2^20 float4 = exactly 4 batches, so each
// thread's within-batch position is loop-invariant -> pe computed once in registers.
//
// R4: same as R3 but with native clang ext_vector_type for the streams —
// __builtin_nontemporal_load/store rejects HIP_vector_type but accepts
// native vectors. Two-phase body: 8 outstanding dwordx4 loads, then add+store.

typedef float vf4 __attribute__((ext_vector_type(4)));

#define TOTAL_F4   (1u << 23)        // 32*256*64*64 floats / 4
#define THREADS    256
#define BLOCKS     4096              // 2^20 threads total
#define STRIDE_F4  (1u << 20)        // BLOCKS*THREADS; = 4 batches worth of float4
#define ITERS      8                 // TOTAL_F4 / STRIDE_F4

__global__ __launch_bounds__(THREADS) void pe_add_kernel(
    const float* __restrict__ x,
    const float* __restrict__ Wm,    // [256, 4] row-major
    const float* __restrict__ bias,  // [256]
    float* __restrict__ out)
{
    const unsigned t = blockIdx.x * (unsigned)THREADS + threadIdx.x;   // [0, 2^20)

    // Within-batch position (invariant across iterations).
    const unsigned p  = t & ((1u << 18) - 1u);   // float4 index within a batch
    const unsigned g  = p << 2;                  // element index within a batch
    const unsigned c2 = g & 255u;                // channel of first element (multiple of 4)
    const unsigned j2 = (g >> 8) & 63u;
    const unsigned i2 = (g >> 14) & 63u;

    const float u = (float)j2 * (1.0f / 63.0f);
    const float v = (float)i2 * (1.0f / 63.0f);

    // W rows c2 .. c2+3 : 4 aligned 16B loads (Wm is [256][4]). L1/L2-hot.
    const vf4* Wrows = reinterpret_cast<const vf4*>(Wm);
    const vf4 wa = Wrows[c2 + 0];
    const vf4 wb = Wrows[c2 + 1];
    const vf4 wc = Wrows[c2 + 2];
    const vf4 wd = Wrows[c2 + 3];

    const float pe0 = u * (wa.x - wa.z) + v * (wa.y - wa.w) + (wa.z + wa.w + bias[c2 + 0]);
    const float pe1 = u * (wb.x - wb.z) + v * (wb.y - wb.w) + (wb.z + wb.w + bias[c2 + 1]);
    const float pe2 = u * (wc.x - wc.z) + v * (wc.y - wc.w) + (wc.z + wc.w + bias[c2 + 2]);
    const float pe3 = u * (wd.x - wd.z) + v * (wd.y - wd.w) + (wd.z + wd.w + bias[c2 + 3]);

    const vf4 pe = { pe0, pe1, pe2, pe3 };

    const vf4* xp = reinterpret_cast<const vf4*>(x);
    vf4*       op = reinterpret_cast<vf4*>(out);

    // Phase 1: issue all 8 loads (independent -> 8 outstanding vmem/wave).
    vf4 xv[ITERS];
#pragma unroll
    for (unsigned n = 0; n < ITERS; ++n) {
        const size_t f = (size_t)t + (size_t)n * STRIDE_F4;
        xv[n] = __builtin_nontemporal_load(&xp[f]);
    }

    // Phase 2: add pe, store (nontemporal — write-once stream).
#pragma unroll
    for (unsigned n = 0; n < ITERS; ++n) {
        const size_t f = (size_t)t + (size_t)n * STRIDE_F4;
        __builtin_nontemporal_store(xv[n] + pe, &op[f]);
    }
}

extern "C" void kernel_launch(void* const* d_in, const int* in_sizes, int n_in,
                              void* d_out, int out_size, void* d_ws, size_t ws_size,
                              hipStream_t stream) {
    const float* x    = (const float*)d_in[0];  // [32, 256, 64, 64] fp32
    const float* Wm   = (const float*)d_in[1];  // [256, 4] fp32
    const float* bias = (const float*)d_in[2];  // [256] fp32
    float* out = (float*)d_out;                 // [32, 256, 64, 64] fp32

    pe_add_kernel<<<dim3(BLOCKS), dim3(THREADS), 0, stream>>>(x, Wm, bias, out);
}